// Round 8
// baseline (222.738 us; speedup 1.0000x reference)
//
#include <hip/hip_runtime.h>

typedef __attribute__((ext_vector_type(8))) short s16x8;
typedef __attribute__((ext_vector_type(4))) float f32x4;
typedef unsigned short u16;
typedef unsigned int   u32;

#define MFMA16(a,b,c) __builtin_amdgcn_mfma_f32_16x16x32_bf16((a),(b),(c),0,0,0)

__device__ __forceinline__ float bf2f(u16 u){
  u32 x = ((u32)u) << 16; float f; __builtin_memcpy(&f, &x, 4); return f;
}
__device__ __forceinline__ u16 f2bf(float f){
  u32 x; __builtin_memcpy(&x, &f, 4);
  x += 0x7FFFu + ((x >> 16) & 1u);   // round-to-nearest-even
  return (u16)(x >> 16);
}
#if defined(__has_builtin) && __has_builtin(__builtin_amdgcn_cvt_pk_bf16_f32)
__device__ __forceinline__ u32 pack2(float a, float b){
  return __builtin_bit_cast(u32, __builtin_amdgcn_cvt_pk_bf16_f32(a, b));
}
#else
__device__ __forceinline__ u32 pack2(float a, float b){
  return (u32)f2bf(a) | ((u32)f2bf(b) << 16);
}
#endif
#if defined(__has_builtin) && __has_builtin(__builtin_amdgcn_exp2f)
__device__ __forceinline__ float fexp2(float x){ return __builtin_amdgcn_exp2f(x); }
#else
extern "C" __device__ float __ocml_native_exp2_f32(float);
__device__ __forceinline__ float fexp2(float x){ return __ocml_native_exp2_f32(x); }
#endif

// w1_swz : [ntile=16][kc=22][lane=64][8]
//          B[k=kc*32+(lane>>4)*8+j][n=ntile*16+(lane&15)]  (zero-padded k>=676)
// wp[l*4+h] : [32 rows o][stride 40 f]; rows 0..25 = W^T, 26 = W@a_src,
//          27 = W@a_dst, 28..31/cols>=26 = 0.

// ---------------------------------------------------------------------------
// prep: single kernel, two roles by blockIdx (saves one ~18us dispatch):
//   blocks 0..351  : W1 -> w1_swz (k-pair per block, 256 threads = n)
//   blocks 352..363: wprep for lh = blockIdx-352
// ---------------------------------------------------------------------------
__global__ __launch_bounds__(256) void prep_kernel(
    const float* __restrict__ W, const float* __restrict__ a_src,
    const float* __restrict__ a_dst, const float* __restrict__ W1,
    u16* __restrict__ w1t, u16* __restrict__ wp)
{
  const int t = threadIdx.x;
  if (blockIdx.x < 352){
    const int k = blockIdx.x * 2;            // 0..702 even
    const int n = t;
    float v0 = 0.f, v1 = 0.f;
    if (k < 676)     v0 = W1[(size_t)k*256 + n];
    if (k + 1 < 676) v1 = W1[(size_t)(k+1)*256 + n];
    const int ntile = n >> 4, lm = n & 15;
    const int kc = k >> 5, q16 = (k >> 3) & 3, j = k & 7;
    u16* dst = w1t + ((((size_t)ntile*22 + kc)*64 + q16*16 + lm) << 3) + j;
    *(u32*)dst = pack2(v0, v1);
  } else {
    const int lh = blockIdx.x - 352;         // 0..11 = l*4+h
    const float* Wlh = W + lh*676;           // [f][o]
    u16* dst = wp + lh*32*40;
    for (int e = t; e < 1280; e += 256) dst[e] = 0;
    __syncthreads();
    for (int e = t; e < 676; e += 256){ int f = e/26, o = e%26; dst[o*40 + f] = f2bf(Wlh[f*26 + o]); }
    if (t < 52){
      int sel = t/26, f = t%26;
      const float* av = (sel ? a_dst : a_src) + lh*26;
      float acc = 0.f;
      #pragma unroll
      for (int o = 0; o < 26; ++o) acc += Wlh[f*26 + o]*av[o];
      dst[(26 + sel)*40 + f] = f2bf(acc);
    }
  }
}

// ---------------------------------------------------------------------------
// GAT kernel: 3 fused layers + fused MLP head. One block = 8 batch elements,
// 512 threads (8 waves), grid 2048, 2 blocks/CU (same 4 waves/SIMD as R6).
// matmul1: wave pair (h=w&3, half=w>>2) covers 13 exact 16-row tiles.
// matmul2: wave w = batch w (identical per-wave work to R7).
// head: wave w = ntiles {2w,2w+1}; A rows m hold batch m&7 (2x dup) ->
//       w1t L2 duplication halved vs R7 (720 MB).
// LDS: xs[208][40] 16.6KB, hsT[4][32][220] 56.4KB (stride 220 => <=2-way
//      bank aliasing), part 0.8KB; total 73.8KB.
// ---------------------------------------------------------------------------
__global__ __launch_bounds__(512, 4) void gat_kernel(
    const float* __restrict__ x, const u16* __restrict__ wp,
    const u16* __restrict__ w1t, const float* __restrict__ b1,
    const float* __restrict__ w2, const float* __restrict__ b2,
    float* __restrict__ out)
{
  __shared__ __align__(16) u16 xs [208*40];
  __shared__ __align__(16) u16 hsT[4*32*220 + 16];
  __shared__ float part[8][8][3];

  const int tid  = threadIdx.x;
  const int w    = tid >> 6;           // 0..7
  const int lane = tid & 63;
  const int q    = lane >> 4;
  const int lm   = lane & 15;
  const int b0   = blockIdx.x * 8;
  const float L2E = 1.4426950408889634f;

  // zero hsT padding once (rows 28..31 all cols; cols 208..219 rows 0..27; tail)
  for (int e = tid; e < 3520; e += 512){            // rows (o&31)>=28
    int r = e/220, c = e%220; int h = r>>2, rr = 28 + (r&3);
    hsT[(h*32 + rr)*220 + c] = 0;
  }
  for (int e = tid; e < 1344; e += 512){            // cols 208..219, rows 0..27
    int r = e/12, c = 208 + e%12; int h = r/28, rr = r%28;
    hsT[(h*32 + rr)*220 + c] = 0;
  }
  if (tid < 16) hsT[4*32*220 + tid] = 0;
  // zero xs padding: cols 26..39, all 208 rows (208 = 13 exact 16-row tiles)
  for (int e = tid; e < 208*14; e += 512){ int r = e/14, c = 26 + e%14; xs[r*40 + c] = 0; }
  // load x (fp32 pairs -> packed bf16)
  for (int pp = tid; pp < 2704; pp += 512){
    int b = pp/338, r2 = pp%338, n = r2/13, p = r2%13;
    float2 v = *(const float2*)&x[(b0 + b)*676 + n*26 + 2*p];
    *(u32*)&xs[(b*26 + n)*40 + 2*p] = pack2(v.x, v.y);
  }

  const int h4   = w & 3;              // head for matmul1
  const int half = w >> 2;             // row-half for matmul1
  for (int l = 0; l < 3; ++l){
    __syncthreads();

    // ---- matmul1: h_aug = x @ W_aug ----
    {
      s16x8 bfr0 = *(const s16x8*)&wp[((l*4 + h4)*32      + lm)*40 + q*8];
      s16x8 bfr1 = *(const s16x8*)&wp[((l*4 + h4)*32 + 16 + lm)*40 + q*8];
      const int nt_ = 7 - half;        // half0: t=0..6, half1: t=7..12
      for (int tt = 0; tt < nt_; ++tt){
        int t = half*7 + tt;
        s16x8 af = *(const s16x8*)&xs[(t*16 + lm)*40 + q*8];
        f32x4 z = {0.f,0.f,0.f,0.f};
        f32x4 d0 = MFMA16(af, bfr0, z);
        f32x4 d1 = MFMA16(af, bfr1, z);
        int gr0 = t*16 + q*4;
        { uint2 uu; uu.x = pack2(d0[0], d0[1]); uu.y = pack2(d0[2], d0[3]);
          *(uint2*)&hsT[(h4*32 + lm)*220 + gr0] = uu; }
        if (lm < 12){
          uint2 uu; uu.x = pack2(d1[0], d1[1]); uu.y = pack2(d1[2], d1[3]);
          *(uint2*)&hsT[(h4*32 + 16 + lm)*220 + gr0] = uu; }
      }
    }
    __syncthreads();

    // ---- matmul2: out^T = h^T @ alpha^T, softmax in-register (batch = w)
    {
      f32x4 acc00 = {0,0,0,0}, acc01 = acc00, acc10 = acc00, acc11 = acc00;
      const int j0 = q*8;
      const int w26 = w*26;
      #pragma unroll
      for (int h = 0; h < 4; ++h){
        s16x8 am0, am1;
        {
          int base = (h*32 + lm)*220 + w26 + j0;
          uint4 uu = { *(const u32*)&hsT[base],   *(const u32*)&hsT[base+2],
                       *(const u32*)&hsT[base+4], *(const u32*)&hsT[base+6] };
          am0 = __builtin_bit_cast(s16x8, uu);
          base = (h*32 + 16 + lm)*220 + w26 + j0;
          uint4 vv = { *(const u32*)&hsT[base],   *(const u32*)&hsT[base+2],
                       *(const u32*)&hsT[base+4], *(const u32*)&hsT[base+6] };
          am1 = __builtin_bit_cast(s16x8, vv);
        }
        float sd2[8];
        {
          int base = (h*32 + 27)*220 + w26 + j0;
          #pragma unroll
          for (int u = 0; u < 4; ++u){
            u32 v = *(const u32*)&hsT[base + 2*u];
            sd2[2*u]   = bf2f((u16)(v & 0xFFFFu)) * L2E;
            sd2[2*u+1] = bf2f((u16)(v >> 16))     * L2E;
          }
          #pragma unroll
          for (int jj = 0; jj < 8; ++jj)
            if (j0 + jj >= 26) sd2[jj] = -1e30f;   // exp2 -> 0, kills j-pad
        }
        #pragma unroll
        for (int nt = 0; nt < 2; ++nt){
          int i = nt*16 + lm;
          float si2 = bf2f(hsT[(h*32 + 26)*220 + w26 + i]) * L2E;  // i>=26 junk contained
          float p[8]; float loc = 0.f;
          #pragma unroll
          for (int jj = 0; jj < 8; ++jj){
            float e = si2 + sd2[jj];
            e = fmaxf(e, 0.2f*e);                  // leaky_relu (log2 domain)
            float pv = fexp2(e);
            p[jj] = pv; loc += pv;
          }
          float tot = loc;
          tot += __shfl_xor(tot, 16);
          tot += __shfl_xor(tot, 32);
          float rinv = __builtin_amdgcn_rcpf(tot);
          uint4 bu = { pack2(p[0]*rinv, p[1]*rinv), pack2(p[2]*rinv, p[3]*rinv),
                       pack2(p[4]*rinv, p[5]*rinv), pack2(p[6]*rinv, p[7]*rinv) };
          s16x8 bfrag = __builtin_bit_cast(s16x8, bu);
          if (nt == 0){ acc00 = MFMA16(am0, bfrag, acc00);
                        acc10 = MFMA16(am1, bfrag, acc10); }
          else        { acc01 = MFMA16(am0, bfrag, acc01);
                        acc11 = MFMA16(am1, bfrag, acc11); }
        }
      }
      // epilogue: mean heads (x0.25), ELU, write next-layer xs (bf16)
      #pragma unroll
      for (int nt = 0; nt < 2; ++nt){
        int i = nt*16 + lm;
        if (i < 26){
          int rowb = (w*26 + i)*40;
          #pragma unroll
          for (int mt = 0; mt < 2; ++mt){
            f32x4 a = (mt == 0) ? (nt == 0 ? acc00 : acc01)
                                : (nt == 0 ? acc10 : acc11);
            int f0 = mt*16 + q*4;
            float v0 = a[0]*0.25f, v1 = a[1]*0.25f, v2 = a[2]*0.25f, v3 = a[3]*0.25f;
            v0 = (v0 > 0.f) ? v0 : (fexp2(v0*L2E) - 1.f);
            v1 = (v1 > 0.f) ? v1 : (fexp2(v1*L2E) - 1.f);
            v2 = (v2 > 0.f) ? v2 : (fexp2(v2*L2E) - 1.f);
            v3 = (v3 > 0.f) ? v3 : (fexp2(v3*L2E) - 1.f);
            if (f0 <= 20){
              uint2 uu; uu.x = pack2(v0, v1); uu.y = pack2(v2, v3);
              *(uint2*)&xs[rowb + f0] = uu;
            } else if (f0 == 24){
              *(u32*)&xs[rowb + 24] = pack2(v0, v1);
            }
          }
        }
      }
    }
  }

  // ---------------- fused MLP head ----------------
  // per-lane coefficients for cols n = (w*2+nt)*16 + lm (issue early)
  float b1l[2], w2l[2][3];
  #pragma unroll
  for (int nt = 0; nt < 2; ++nt){
    int col = (w*2 + nt)*16 + lm;
    b1l[nt]    = b1[col];
    w2l[nt][0] = w2[col*3]; w2l[nt][1] = w2[col*3+1]; w2l[nt][2] = w2[col*3+2];
  }

  __syncthreads();                        // hsT reads done -> safe to alias
  u16* xc = hsT;                          // xc[8][736] flat bf16, k-padded 0
  for (int e = tid; e < 8*368; e += 512){ // u32 pairs, row stride 736
    int bb = e/368, p = e%368, k = 2*p;
    u32 v = 0;
    if (k < 676){ int n = k/26, f = k - n*26; v = *(const u32*)&xs[(bb*26 + n)*40 + f]; }
    *(u32*)&xc[bb*736 + k] = v;
  }
  __syncthreads();

  {
    f32x4 acc[2];
    acc[0] = (f32x4){0.f,0.f,0.f,0.f}; acc[1] = acc[0];
    const int bb = lane & 7;              // A row m = lm holds batch lm&7
    const u16* bbase = w1t + (((size_t)w*2)*22*64 + lane)*8;
    #pragma unroll
    for (int kc = 0; kc < 22; ++kc){
      s16x8 afr = *(const s16x8*)&xc[bb*736 + kc*32 + q*8];
      #pragma unroll
      for (int nt = 0; nt < 2; ++nt){
        s16x8 bfr = *(const s16x8*)(bbase + (size_t)(nt*22 + kc)*64*8);
        acc[nt] = MFMA16(afr, bfr, acc[nt]);
      }
    }
    // D row = q*4+r -> batch (q*4+r)&7: q=0 -> r, q=1 -> 4+r; q>=2 duplicates.
    float po[4][3];
    #pragma unroll
    for (int r = 0; r < 4; ++r){
      float s0 = 0.f, s1 = 0.f, s2 = 0.f;
      #pragma unroll
      for (int nt = 0; nt < 2; ++nt){
        float hv = acc[nt][r] + b1l[nt];
        hv = fmaxf(hv, 0.2f*hv);          // leaky_relu 0.2
        s0 += hv*w2l[nt][0]; s1 += hv*w2l[nt][1]; s2 += hv*w2l[nt][2];
      }
      po[r][0] = s0; po[r][1] = s1; po[r][2] = s2;
    }
    #pragma unroll
    for (int m = 1; m < 16; m <<= 1)
      #pragma unroll
      for (int r = 0; r < 4; ++r)
        #pragma unroll
        for (int kk = 0; kk < 3; ++kk)
          po[r][kk] += __shfl_xor(po[r][kk], m);
    if (lm == 0 && q < 2){                // lanes 0 and 16: batches q*4+r
      #pragma unroll
      for (int r = 0; r < 4; ++r)
        #pragma unroll
        for (int kk = 0; kk < 3; ++kk)
          part[w][q*4 + r][kk] = po[r][kk];
    }
  }
  __syncthreads();
  if (tid < 24){
    int r = tid/3, kk = tid - r*3;
    float o = b2[kk];
    #pragma unroll
    for (int ww = 0; ww < 8; ++ww) o += part[ww][r][kk];
    out[(b0 + r)*3 + kk] = o;
  }
}

extern "C" void kernel_launch(void* const* d_in, const int* in_sizes, int n_in,
                              void* d_out, int out_size, void* d_ws, size_t ws_size,
                              hipStream_t stream)
{
  (void)in_sizes; (void)n_in; (void)out_size; (void)ws_size;
  const float* x     = (const float*)d_in[1];
  const float* W     = (const float*)d_in[2];
  const float* a_src = (const float*)d_in[3];
  const float* a_dst = (const float*)d_in[4];
  const float* W1    = (const float*)d_in[5];
  const float* b1    = (const float*)d_in[6];
  const float* W2    = (const float*)d_in[7];
  const float* b2    = (const float*)d_in[8];
  float* out = (float*)d_out;

  u16* w1t = (u16*)d_ws;                       // [16][22][64][8] bf16 (swz)
  u16* wp  = w1t + (size_t)16*22*64*8;         // [12][32][40]    bf16

  hipLaunchKernelGGL(prep_kernel, dim3(364),  dim3(256), 0, stream,
                     W, a_src, a_dst, W1, w1t, wp);
  hipLaunchKernelGGL(gat_kernel,  dim3(2048), dim3(512), 0, stream,
                     x, wp, w1t, b1, W2, b2, out);
}

// Round 9
// 215.879 us; speedup vs baseline: 1.0318x; 1.0318x over previous
//
#include <hip/hip_runtime.h>

typedef __attribute__((ext_vector_type(8))) short s16x8;
typedef __attribute__((ext_vector_type(4))) float f32x4;
typedef unsigned short u16;
typedef unsigned int   u32;

#define MFMA16(a,b,c) __builtin_amdgcn_mfma_f32_16x16x32_bf16((a),(b),(c),0,0,0)

__device__ __forceinline__ float bf2f(u16 u){
  u32 x = ((u32)u) << 16; float f; __builtin_memcpy(&f, &x, 4); return f;
}
__device__ __forceinline__ u16 f2bf(float f){
  u32 x; __builtin_memcpy(&x, &f, 4);
  x += 0x7FFFu + ((x >> 16) & 1u);   // round-to-nearest-even
  return (u16)(x >> 16);
}
#if defined(__has_builtin) && __has_builtin(__builtin_amdgcn_cvt_pk_bf16_f32)
__device__ __forceinline__ u32 pack2(float a, float b){
  return __builtin_bit_cast(u32, __builtin_amdgcn_cvt_pk_bf16_f32(a, b));
}
#else
__device__ __forceinline__ u32 pack2(float a, float b){
  return (u32)f2bf(a) | ((u32)f2bf(b) << 16);
}
#endif
#if defined(__has_builtin) && __has_builtin(__builtin_amdgcn_exp2f)
__device__ __forceinline__ float fexp2(float x){ return __builtin_amdgcn_exp2f(x); }
#else
extern "C" __device__ float __ocml_native_exp2_f32(float);
__device__ __forceinline__ float fexp2(float x){ return __ocml_native_exp2_f32(x); }
#endif

// Layouts:
// xf_swz : [mtile=1024][kc=22][lane=64][8]  A[m=lane&15][k=kc*32+(lane>>4)*8+j]
// w1_swz : [ntile=16]  [kc=22][lane=64][8]  B[k=...][n=ntile*16+(lane&15)]
// wp[l*4+h] : [32 rows o][stride 40 f]; rows 0..25 = W^T, 26 = W@a_src,
//             27 = W@a_dst, 28..31 / cols>=26 = 0.
// gat LDS (pad-32 node layout):
//   xs [128 rows = b*32+n][stride 36]  (n>=26 rows zero, f>=26 cols zero)
//   hsT[4 heads][28 rows o][stride 132] cols = b*32+n; o26 = s_src,
//      o27 = s_dst with cols n>=26 poisoned to -1e30 (kills softmax k-tail;
//      A-side zeros kill the B-value side). 8B-aligned strides, <=4-way banks.

// ---------------------------------------------------------------------------
// prep: blocks 0..351: W1 -> w1_swz; blocks 352..363: wp for lh = blk-352.
// ---------------------------------------------------------------------------
__global__ __launch_bounds__(256) void prep_kernel(
    const float* __restrict__ W, const float* __restrict__ a_src,
    const float* __restrict__ a_dst, const float* __restrict__ W1,
    u16* __restrict__ w1t, u16* __restrict__ wp)
{
  const int t = threadIdx.x;
  if (blockIdx.x < 352){
    const int k = blockIdx.x * 2;            // 0..702 even
    const int n = t;
    float v0 = 0.f, v1 = 0.f;
    if (k < 676)     v0 = W1[(size_t)k*256 + n];
    if (k + 1 < 676) v1 = W1[(size_t)(k+1)*256 + n];
    const int ntile = n >> 4, lm = n & 15;
    const int kc = k >> 5, q16 = (k >> 3) & 3, j = k & 7;
    u16* dst = w1t + ((((size_t)ntile*22 + kc)*64 + q16*16 + lm) << 3) + j;
    *(u32*)dst = pack2(v0, v1);
  } else {
    const int lh = blockIdx.x - 352;         // 0..11 = l*4+h
    const float* Wlh = W + lh*676;           // [f][o]
    u16* dst = wp + lh*32*40;
    for (int e = t; e < 1280; e += 256) dst[e] = 0;
    __syncthreads();
    for (int e = t; e < 676; e += 256){ int f = e/26, o = e%26; dst[o*40 + f] = f2bf(Wlh[f*26 + o]); }
    if (t < 52){
      int sel = t/26, f = t%26;
      const float* av = (sel ? a_dst : a_src) + lh*26;
      float acc = 0.f;
      #pragma unroll
      for (int o = 0; o < 26; ++o) acc += Wlh[f*26 + o]*av[o];
      dst[(26 + sel)*40 + f] = f2bf(acc);
    }
  }
}

// ---------------------------------------------------------------------------
// GAT kernel: 3 fused layers. One block = 4 batch elements, 256 threads,
// 4 blocks/CU (38.9 KB LDS). matmul1: wave=head, 8 exact 16-row tiles.
// matmul2: wave=batch, softmax in-register; pad-32 layout removes j-guards.
// Tail: destination-linear swizzled xf store (R6-proven).
// ---------------------------------------------------------------------------
__global__ __launch_bounds__(256, 4) void gat_kernel(
    const float* __restrict__ x, const u16* __restrict__ wp,
    u16* __restrict__ xf)
{
  __shared__ __align__(16) u16 xs [128*36];
  __shared__ __align__(16) u16 hsT[4*28*132];

  const int tid  = threadIdx.x;
  const int w    = tid >> 6;
  const int lane = tid & 63;
  const int q    = lane >> 4;
  const int lm   = lane & 15;
  const int lmc  = (lm < 11) ? lm : 11;      // clamp for am1 row reads
  const int b0   = blockIdx.x * 4;
  const float L2E = 1.4426950408889634f;

  // s_dst pad-column poison masks (matmul1 d1, odd t): col&31 = 16+4q+r >= 26
  const bool pm01 = (lm == 11) && (q == 3);  // r = 0,1
  const bool pm23 = (lm == 11) && (q >= 2);  // r = 2,3

  // zero xs padding (disjoint from data; no barrier needed before staging):
  for (int e = tid; e < 864; e += 256){      // rows n>=26, all 36 cols
    int b = e/216, r = e%216, n = 26 + r/36, c = r%36;
    xs[(b*32 + n)*36 + c] = 0;
  }
  for (int e = tid; e < 1040; e += 256){     // data rows, cols 26..35
    int r = e/10, c = 26 + e%10; int b = r/26, n = r%26;
    xs[(b*32 + n)*36 + c] = 0;
  }
  // load x (fp32 pairs -> packed bf16)
  for (int pp = tid; pp < 1352; pp += 256){
    int b = pp/338, r2 = pp%338, n = r2/13, p = r2%13;
    float2 v = *(const float2*)&x[(b0 + b)*676 + n*26 + 2*p];
    *(u32*)&xs[(b*32 + n)*36 + 2*p] = pack2(v.x, v.y);
  }

  for (int l = 0; l < 3; ++l){
    __syncthreads();

    // ---- matmul1: h_aug = x @ W_aug  (head = w) ----
    {
      s16x8 bfr0 = *(const s16x8*)&wp[((l*4 + w)*32      + lm)*40 + q*8];
      s16x8 bfr1 = *(const s16x8*)&wp[((l*4 + w)*32 + 16 + lm)*40 + q*8];
      #pragma unroll
      for (int t = 0; t < 8; ++t){
        s16x8 af = *(const s16x8*)&xs[(t*16 + lm)*36 + q*8];
        f32x4 z = {0.f,0.f,0.f,0.f};
        f32x4 d0 = MFMA16(af, bfr0, z);
        f32x4 d1 = MFMA16(af, bfr1, z);
        const int gr0 = t*16 + q*4;
        if (t & 1){                          // poison s_dst pad cols (o=27)
          d1[0] = pm01 ? -1e30f : d1[0];
          d1[1] = pm01 ? -1e30f : d1[1];
          d1[2] = pm23 ? -1e30f : d1[2];
          d1[3] = pm23 ? -1e30f : d1[3];
        }
        { uint2 uu; uu.x = pack2(d0[0], d0[1]); uu.y = pack2(d0[2], d0[3]);
          *(uint2*)&hsT[(w*28 + lm)*132 + gr0] = uu; }
        if (lm < 12){
          uint2 uu; uu.x = pack2(d1[0], d1[1]); uu.y = pack2(d1[2], d1[3]);
          *(uint2*)&hsT[(w*28 + 16 + lm)*132 + gr0] = uu; }
      }
    }
    __syncthreads();

    // ---- matmul2: out^T = h^T @ alpha^T, softmax in-register (batch = w)
    {
      f32x4 acc00 = {0,0,0,0}, acc01 = acc00, acc10 = acc00, acc11 = acc00;
      const int j0  = q*8;
      const int b32 = w*32;
      #pragma unroll
      for (int h = 0; h < 4; ++h){
        s16x8 am0, am1;
        {
          int base = (h*28 + lm)*132 + b32 + j0;
          uint4 uu = { *(const u32*)&hsT[base],   *(const u32*)&hsT[base+2],
                       *(const u32*)&hsT[base+4], *(const u32*)&hsT[base+6] };
          am0 = __builtin_bit_cast(s16x8, uu);
          base = (h*28 + 16 + lmc)*132 + b32 + j0;
          uint4 vv = { *(const u32*)&hsT[base],   *(const u32*)&hsT[base+2],
                       *(const u32*)&hsT[base+4], *(const u32*)&hsT[base+6] };
          am1 = __builtin_bit_cast(s16x8, vv);
        }
        float sd2[8];
        {
          int base = (h*28 + 27)*132 + b32 + j0;
          #pragma unroll
          for (int u = 0; u < 4; ++u){
            u32 v = *(const u32*)&hsT[base + 2*u];
            sd2[2*u]   = bf2f((u16)(v & 0xFFFFu)) * L2E;
            sd2[2*u+1] = bf2f((u16)(v >> 16))     * L2E;
          }
        }
        #pragma unroll
        for (int nt = 0; nt < 2; ++nt){
          int i = nt*16 + lm;
          float si2 = bf2f(hsT[(h*28 + 26)*132 + b32 + i]) * L2E;
          float p[8]; float loc = 0.f;
          #pragma unroll
          for (int jj = 0; jj < 8; ++jj){
            float e = si2 + sd2[jj];
            e = fmaxf(e, 0.2f*e);                  // leaky_relu (log2 domain)
            float pv = fexp2(e);                   // pad cols: exp2(-1e30)=0
            p[jj] = pv; loc += pv;
          }
          float tot = loc;
          tot += __shfl_xor(tot, 16);
          tot += __shfl_xor(tot, 32);
          float rinv = __builtin_amdgcn_rcpf(tot);
          uint4 bu = { pack2(p[0]*rinv, p[1]*rinv), pack2(p[2]*rinv, p[3]*rinv),
                       pack2(p[4]*rinv, p[5]*rinv), pack2(p[6]*rinv, p[7]*rinv) };
          s16x8 bfrag = __builtin_bit_cast(s16x8, bu);
          if (nt == 0){ acc00 = MFMA16(am0, bfrag, acc00);
                        acc10 = MFMA16(am1, bfrag, acc10); }
          else        { acc01 = MFMA16(am0, bfrag, acc01);
                        acc11 = MFMA16(am1, bfrag, acc11); }
        }
      }
      // epilogue: mean heads (x0.25), ELU, write next-layer xs (bf16)
      #pragma unroll
      for (int nt = 0; nt < 2; ++nt){
        int i = nt*16 + lm;
        if (i < 26){
          int rowb = (w*32 + i)*36;
          #pragma unroll
          for (int mt = 0; mt < 2; ++mt){
            f32x4 a = (mt == 0) ? (nt == 0 ? acc00 : acc01)
                                : (nt == 0 ? acc10 : acc11);
            int f0 = mt*16 + q*4;
            float v0 = a[0]*0.25f, v1 = a[1]*0.25f, v2 = a[2]*0.25f, v3 = a[3]*0.25f;
            v0 = (v0 > 0.f) ? v0 : (fexp2(v0*L2E) - 1.f);
            v1 = (v1 > 0.f) ? v1 : (fexp2(v1*L2E) - 1.f);
            v2 = (v2 > 0.f) ? v2 : (fexp2(v2*L2E) - 1.f);
            v3 = (v3 > 0.f) ? v3 : (fexp2(v3*L2E) - 1.f);
            if (f0 <= 20){
              uint2 uu; uu.x = pack2(v0, v1); uu.y = pack2(v2, v3);
              *(uint2*)&xs[rowb + f0] = uu;
            } else if (f0 == 24){
              *(u32*)&xs[rowb + 24] = pack2(v0, v1);
            }
          }
        }
      }
    }
  }
  __syncthreads();
  // store x_final into swizzled A-fragment layout, destination-linear:
  // each 16-thread group writes one contiguous 64B chunk (4 rows x 8 bf16).
  {
    const int mtile = b0 >> 4;
    const int lrow0 = b0 & 15;               // 0,4,8,12
    u16* dstb = xf + (size_t)mtile*22*64*8;
    for (int e = tid; e < 1408; e += 256){
      int chunk = e >> 4;                    // 0..87 = kc*4 + q16
      int u     = e & 15;                    // u32 slot within 64B chunk
      int kc = chunk >> 2, q16 = chunk & 3;
      int bb = u >> 2;                       // local batch 0..3
      int j2 = (u & 3) * 2;
      int k  = kc*32 + q16*8 + j2;           // flat feature (0..703, even)
      u32 v = 0;
      if (k < 676){ int n = k/26, f = k - n*26; v = *(const u32*)&xs[(bb*32 + n)*36 + f]; }
      *(u32*)&dstb[((kc*64 + q16*16 + lrow0 + bb) << 3) + j2] = v;
    }
  }
}

// ---------------------------------------------------------------------------
// MLP: out = leaky(xf @ W1 + b1, 0.2) @ W2 + b2.  BM=32, grid 512 (2/CU,
// 8 waves/CU). Barrier-free, LDS-free K-loop with 2-stage register prefetch;
// all fragments coalesced (1KB/wave) from swizzled layouts. Fused W2 head.
// ---------------------------------------------------------------------------
__global__ __launch_bounds__(256, 2) void mlp_kernel(
    const u16* __restrict__ xf, const u16* __restrict__ w1t,
    const float* __restrict__ b1, const float* __restrict__ w2,
    const float* __restrict__ b2, float* __restrict__ out)
{
  __shared__ float b1s[256];
  __shared__ float w2s[256*3];
  __shared__ float part[4*32*3];

  const int tid  = threadIdx.x;
  const int w    = tid >> 6;
  const int lane = tid & 63;
  const int q    = lane >> 4;
  const int lm   = lane & 15;
  const int m0   = blockIdx.x * 32;
  const int mt0  = blockIdx.x * 2;         // 2 mtiles per block

  b1s[tid] = b1[tid];
  for (int e = tid; e < 768; e += 256) w2s[e] = w2[e];

  f32x4 acc[2][4];
  #pragma unroll
  for (int a = 0; a < 2; ++a)
    #pragma unroll
    for (int b = 0; b < 4; ++b) acc[a][b] = (f32x4){0.f,0.f,0.f,0.f};

  const u16* abase = xf  + ((size_t)mt0*22*64 + lane) * 8;
  const u16* bbase = w1t + (((size_t)w*4)*22*64 + lane) * 8;

  s16x8 af[2], bf[4], afn[2], bfn[4];
  #pragma unroll
  for (int mt = 0; mt < 2; ++mt) af[mt] = *(const s16x8*)(abase + (size_t)(mt*22)*64*8);
  #pragma unroll
  for (int nt = 0; nt < 4; ++nt) bf[nt] = *(const s16x8*)(bbase + (size_t)(nt*22)*64*8);

  #pragma unroll
  for (int kc = 0; kc < 22; ++kc){
    if (kc < 21){
      #pragma unroll
      for (int mt = 0; mt < 2; ++mt)
        afn[mt] = *(const s16x8*)(abase + (size_t)(mt*22 + kc + 1)*64*8);
      #pragma unroll
      for (int nt = 0; nt < 4; ++nt)
        bfn[nt] = *(const s16x8*)(bbase + (size_t)(nt*22 + kc + 1)*64*8);
    }
    #pragma unroll
    for (int mt = 0; mt < 2; ++mt)
      #pragma unroll
      for (int nt = 0; nt < 4; ++nt)
        acc[mt][nt] = MFMA16(af[mt], bf[nt], acc[mt][nt]);
    #pragma unroll
    for (int mt = 0; mt < 2; ++mt) af[mt] = afn[mt];
    #pragma unroll
    for (int nt = 0; nt < 4; ++nt) bf[nt] = bfn[nt];
  }

  // epilogue: +b1, leaky, @W2 partials, reduce over 16 lanes (cols)
  float b1l[4], w2l[4][3];
  #pragma unroll
  for (int nt = 0; nt < 4; ++nt){
    int col = w*64 + nt*16 + lm;
    b1l[nt] = b1s[col];
    w2l[nt][0] = w2s[col*3]; w2l[nt][1] = w2s[col*3+1]; w2l[nt][2] = w2s[col*3+2];
  }
  float po[2][4][3];
  #pragma unroll
  for (int mt = 0; mt < 2; ++mt)
    #pragma unroll
    for (int r = 0; r < 4; ++r){
      float s0 = 0.f, s1 = 0.f, s2 = 0.f;
      #pragma unroll
      for (int nt = 0; nt < 4; ++nt){
        float hv = acc[mt][nt][r] + b1l[nt];
        hv = (hv >= 0.f) ? hv : 0.2f*hv;
        s0 += hv*w2l[nt][0]; s1 += hv*w2l[nt][1]; s2 += hv*w2l[nt][2];
      }
      po[mt][r][0] = s0; po[mt][r][1] = s1; po[mt][r][2] = s2;
    }
  #pragma unroll
  for (int m = 1; m < 16; m <<= 1)
    #pragma unroll
    for (int mt = 0; mt < 2; ++mt)
      #pragma unroll
      for (int r = 0; r < 4; ++r)
        #pragma unroll
        for (int kk = 0; kk < 3; ++kk)
          po[mt][r][kk] += __shfl_xor(po[mt][r][kk], m);
  if (lm == 0){
    #pragma unroll
    for (int mt = 0; mt < 2; ++mt)
      #pragma unroll
      for (int r = 0; r < 4; ++r)
        #pragma unroll
        for (int kk = 0; kk < 3; ++kk)
          part[w*96 + (mt*16 + q*4 + r)*3 + kk] = po[mt][r][kk];
  }
  __syncthreads();
  if (tid < 96){
    int row = tid/3, kk = tid - row*3;
    float o = part[row*3 + kk] + part[96 + row*3 + kk]
            + part[192 + row*3 + kk] + part[288 + row*3 + kk] + b2[kk];
    out[(m0 + row)*3 + kk] = o;
  }
}

extern "C" void kernel_launch(void* const* d_in, const int* in_sizes, int n_in,
                              void* d_out, int out_size, void* d_ws, size_t ws_size,
                              hipStream_t stream)
{
  (void)in_sizes; (void)n_in; (void)out_size; (void)ws_size;
  const float* x     = (const float*)d_in[1];
  const float* W     = (const float*)d_in[2];
  const float* a_src = (const float*)d_in[3];
  const float* a_dst = (const float*)d_in[4];
  const float* W1    = (const float*)d_in[5];
  const float* b1    = (const float*)d_in[6];
  const float* W2    = (const float*)d_in[7];
  const float* b2    = (const float*)d_in[8];
  float* out = (float*)d_out;

  u16* xfinal = (u16*)d_ws;                    // [1024][22][64][8] bf16 (swz)
  u16* w1t    = xfinal + (size_t)16384*704;    // [16][22][64][8]   bf16 (swz)
  u16* wp     = w1t    + 256*704;              // [12][32][40]      bf16

  hipLaunchKernelGGL(prep_kernel, dim3(364),  dim3(256), 0, stream,
                     W, a_src, a_dst, W1, w1t, wp);
  hipLaunchKernelGGL(gat_kernel,  dim3(4096), dim3(256), 0, stream, x, wp, xfinal);
  hipLaunchKernelGGL(mlp_kernel,  dim3(512),  dim3(256), 0, stream,
                     xfinal, w1t, b1, W2, b2, out);
}

// Round 10
// 211.402 us; speedup vs baseline: 1.0536x; 1.0212x over previous
//
#include <hip/hip_runtime.h>

typedef __attribute__((ext_vector_type(8))) short s16x8;
typedef __attribute__((ext_vector_type(4))) float f32x4;
typedef unsigned short u16;
typedef unsigned int   u32;

#define MFMA16(a,b,c) __builtin_amdgcn_mfma_f32_16x16x32_bf16((a),(b),(c),0,0,0)

__device__ __forceinline__ float bf2f(u16 u){
  u32 x = ((u32)u) << 16; float f; __builtin_memcpy(&f, &x, 4); return f;
}
__device__ __forceinline__ float bflo(u32 v){   // low bf16 of packed pair
  u32 x = v << 16; float f; __builtin_memcpy(&f, &x, 4); return f;
}
__device__ __forceinline__ float bfhi(u32 v){   // high bf16 of packed pair
  u32 x = v & 0xFFFF0000u; float f; __builtin_memcpy(&f, &x, 4); return f;
}
__device__ __forceinline__ u16 f2bf(float f){
  u32 x; __builtin_memcpy(&x, &f, 4);
  x += 0x7FFFu + ((x >> 16) & 1u);   // round-to-nearest-even
  return (u16)(x >> 16);
}
#if defined(__has_builtin) && __has_builtin(__builtin_amdgcn_cvt_pk_bf16_f32)
__device__ __forceinline__ u32 pack2(float a, float b){
  return __builtin_bit_cast(u32, __builtin_amdgcn_cvt_pk_bf16_f32(a, b));
}
#else
__device__ __forceinline__ u32 pack2(float a, float b){
  return (u32)f2bf(a) | ((u32)f2bf(b) << 16);
}
#endif
#if defined(__has_builtin) && __has_builtin(__builtin_amdgcn_exp2f)
__device__ __forceinline__ float fexp2(float x){ return __builtin_amdgcn_exp2f(x); }
#else
extern "C" __device__ float __ocml_native_exp2_f32(float);
__device__ __forceinline__ float fexp2(float x){ return __ocml_native_exp2_f32(x); }
#endif

// Layouts:
// xf_swz : [mtile=1024][kc=22][lane=64][8]  A[m=lane&15][k=kc*32+(lane>>4)*8+j]
// w1_swz : [ntile=16]  [kc=22][lane=64][8]  B[k=...][n=ntile*16+(lane&15)]
// wp[l*4+h] : [32 rows o][stride 40 f];
//   rows 0..25 : 0.25 * W^T          (0.25 head-mean folded in — exact, pow2)
//   row  26    : log2e * (W @ a_src)  row 27 : log2e * (W @ a_dst)
//   rows 28..31 / cols >= 26 : 0
// gat LDS (pad-32 nodes):
//   xs [128 rows = b*32+n][stride 36]   (n>=26 rows zero, f>=26 cols zero)
//   hsT[4 heads][28 rows o][stride 136] cols = b*32+n; byte row stride 272 =
//     17*16 -> every fragment row 16B-aligned => am0/am1/sd = ds_read_b128.
//     o27 pad cols poisoned -1e30 (softmax k-tail); value rows pad cols = 0.

// ---------------------------------------------------------------------------
// prep: blocks 0..351: W1 -> w1_swz; blocks 352..363: wp for lh = blk-352.
// ---------------------------------------------------------------------------
__global__ __launch_bounds__(256) void prep_kernel(
    const float* __restrict__ W, const float* __restrict__ a_src,
    const float* __restrict__ a_dst, const float* __restrict__ W1,
    u16* __restrict__ w1t, u16* __restrict__ wp)
{
  const int t = threadIdx.x;
  if (blockIdx.x < 352){
    const int k = blockIdx.x * 2;            // 0..702 even
    const int n = t;
    float v0 = 0.f, v1 = 0.f;
    if (k < 676)     v0 = W1[(size_t)k*256 + n];
    if (k + 1 < 676) v1 = W1[(size_t)(k+1)*256 + n];
    const int ntile = n >> 4, lm = n & 15;
    const int kc = k >> 5, q16 = (k >> 3) & 3, j = k & 7;
    u16* dst = w1t + ((((size_t)ntile*22 + kc)*64 + q16*16 + lm) << 3) + j;
    *(u32*)dst = pack2(v0, v1);
  } else {
    const int lh = blockIdx.x - 352;         // 0..11 = l*4+h
    const float* Wlh = W + lh*676;           // [f][o]
    u16* dst = wp + lh*32*40;
    for (int e = t; e < 1280; e += 256) dst[e] = 0;
    __syncthreads();
    for (int e = t; e < 676; e += 256){      // value rows: 0.25*W^T
      int f = e/26, o = e%26;
      dst[o*40 + f] = f2bf(0.25f * Wlh[f*26 + o]);
    }
    if (t < 52){                             // score rows: log2e * (W@a)
      int sel = t/26, f = t%26;
      const float* av = (sel ? a_dst : a_src) + lh*26;
      float acc = 0.f;
      #pragma unroll
      for (int o = 0; o < 26; ++o) acc += Wlh[f*26 + o]*av[o];
      dst[(26 + sel)*40 + f] = f2bf(1.4426950408889634f * acc);
    }
  }
}

// ---------------------------------------------------------------------------
// GAT kernel: 3 fused layers. One block = 4 batch elements, 256 threads,
// 4 blocks/CU (39.7 KB LDS). matmul1: wave=head, 8 exact 16-row tiles.
// matmul2: wave=batch; softmax in-register from b128 fragment loads.
// Tail: destination-linear swizzled xf store.
// ---------------------------------------------------------------------------
__global__ __launch_bounds__(256, 4) void gat_kernel(
    const float* __restrict__ x, const u16* __restrict__ wp,
    u16* __restrict__ xf)
{
  __shared__ __align__(16) u16 xs [128*36];
  __shared__ __align__(16) u16 hsT[4*28*136];

  const int tid  = threadIdx.x;
  const int w    = tid >> 6;
  const int lane = tid & 63;
  const int q    = lane >> 4;
  const int lm   = lane & 15;
  const int lmc  = (lm < 11) ? lm : 11;      // clamp for am1 row reads
  const int b0   = blockIdx.x * 4;
  const float L2E = 1.4426950408889634f;

  // s_dst pad-column poison masks (matmul1 d1, odd t): col&31 = 16+4q+r >= 26
  const bool pm01 = (lm == 11) && (q == 3);  // r = 0,1
  const bool pm23 = (lm == 11) && (q >= 2);  // r = 2,3

  // zero all of xs (linear u32 loop), then stage data over it
  for (int e = tid; e < 2304; e += 256) ((u32*)xs)[e] = 0;
  __syncthreads();
  // load x (fp32 pairs -> packed bf16)
  for (int pp = tid; pp < 1352; pp += 256){
    int b = pp/338, r2 = pp%338, n = r2/13, p = r2%13;
    float2 v = *(const float2*)&x[(b0 + b)*676 + n*26 + 2*p];
    *(u32*)&xs[(b*32 + n)*36 + 2*p] = pack2(v.x, v.y);
  }

  for (int l = 0; l < 3; ++l){
    __syncthreads();

    // ---- matmul1: h_aug = x @ W_aug  (head = w) ----
    {
      s16x8 bfr0 = *(const s16x8*)&wp[((l*4 + w)*32      + lm)*40 + q*8];
      s16x8 bfr1 = *(const s16x8*)&wp[((l*4 + w)*32 + 16 + lm)*40 + q*8];
      #pragma unroll
      for (int t = 0; t < 8; ++t){
        s16x8 af = *(const s16x8*)&xs[(t*16 + lm)*36 + q*8];
        f32x4 z = {0.f,0.f,0.f,0.f};
        f32x4 d0 = MFMA16(af, bfr0, z);
        f32x4 d1 = MFMA16(af, bfr1, z);
        const int gr0 = t*16 + q*4;
        if (t & 1){                          // poison s_dst pad cols (o=27)
          d1[0] = pm01 ? -1e30f : d1[0];
          d1[1] = pm01 ? -1e30f : d1[1];
          d1[2] = pm23 ? -1e30f : d1[2];
          d1[3] = pm23 ? -1e30f : d1[3];
        }
        { uint2 uu; uu.x = pack2(d0[0], d0[1]); uu.y = pack2(d0[2], d0[3]);
          *(uint2*)&hsT[(w*28 + lm)*136 + gr0] = uu; }
        if (lm < 12){
          uint2 uu; uu.x = pack2(d1[0], d1[1]); uu.y = pack2(d1[2], d1[3]);
          *(uint2*)&hsT[(w*28 + 16 + lm)*136 + gr0] = uu; }
      }
    }
    __syncthreads();

    // ---- matmul2: out^T = h^T @ alpha^T, softmax in-register (batch = w)
    {
      f32x4 acc00 = {0,0,0,0}, acc01 = acc00, acc10 = acc00, acc11 = acc00;
      const int j0  = q*8;
      const int b32 = w*32;
      #pragma unroll
      for (int h = 0; h < 4; ++h){
        // b128 fragment loads (rows 16B-aligned via stride 136)
        s16x8 am0 = *(const s16x8*)&hsT[(h*28      + lm )*136 + b32 + j0];
        s16x8 am1 = *(const s16x8*)&hsT[(h*28 + 16 + lmc)*136 + b32 + j0];
        uint4 sdv = *(const uint4*)&hsT[(h*28 + 27      )*136 + b32 + j0];
        float sd2[8];
        sd2[0] = bflo(sdv.x); sd2[1] = bfhi(sdv.x);
        sd2[2] = bflo(sdv.y); sd2[3] = bfhi(sdv.y);
        sd2[4] = bflo(sdv.z); sd2[5] = bfhi(sdv.z);
        sd2[6] = bflo(sdv.w); sd2[7] = bfhi(sdv.w);
        #pragma unroll
        for (int nt = 0; nt < 2; ++nt){
          int i = nt*16 + lm;
          float si2 = bf2f(hsT[(h*28 + 26)*136 + b32 + i]);  // pre-scaled
          float p[8]; float loc = 0.f;
          #pragma unroll
          for (int jj = 0; jj < 8; ++jj){
            float e = si2 + sd2[jj];
            e = fmaxf(e, 0.2f*e);                  // leaky_relu (log2 domain)
            float pv = fexp2(e);                   // pad cols: exp2(-1e30)=0
            p[jj] = pv; loc += pv;
          }
          float tot = loc;
          tot += __shfl_xor(tot, 16);
          tot += __shfl_xor(tot, 32);
          float rinv = __builtin_amdgcn_rcpf(tot);
          uint4 bu = { pack2(p[0]*rinv, p[1]*rinv), pack2(p[2]*rinv, p[3]*rinv),
                       pack2(p[4]*rinv, p[5]*rinv), pack2(p[6]*rinv, p[7]*rinv) };
          s16x8 bfrag = __builtin_bit_cast(s16x8, bu);
          if (nt == 0){ acc00 = MFMA16(am0, bfrag, acc00);
                        acc10 = MFMA16(am1, bfrag, acc10); }
          else        { acc01 = MFMA16(am0, bfrag, acc01);
                        acc11 = MFMA16(am1, bfrag, acc11); }
        }
      }
      // epilogue: heads pre-meaned (0.25 in wp), ELU, write next-layer xs
      #pragma unroll
      for (int nt = 0; nt < 2; ++nt){
        int i = nt*16 + lm;
        if (i < 26){
          int rowb = (w*32 + i)*36;
          #pragma unroll
          for (int mt = 0; mt < 2; ++mt){
            f32x4 a = (mt == 0) ? (nt == 0 ? acc00 : acc01)
                                : (nt == 0 ? acc10 : acc11);
            int f0 = mt*16 + q*4;
            float v0 = a[0], v1 = a[1], v2 = a[2], v3 = a[3];
            v0 = (v0 > 0.f) ? v0 : (fexp2(v0*L2E) - 1.f);
            v1 = (v1 > 0.f) ? v1 : (fexp2(v1*L2E) - 1.f);
            v2 = (v2 > 0.f) ? v2 : (fexp2(v2*L2E) - 1.f);
            v3 = (v3 > 0.f) ? v3 : (fexp2(v3*L2E) - 1.f);
            if (f0 <= 20){
              uint2 uu; uu.x = pack2(v0, v1); uu.y = pack2(v2, v3);
              *(uint2*)&xs[rowb + f0] = uu;
            } else if (f0 == 24){
              *(u32*)&xs[rowb + 24] = pack2(v0, v1);
            }
          }
        }
      }
    }
  }
  __syncthreads();
  // store x_final into swizzled A-fragment layout, destination-linear:
  // each 16-thread group writes one contiguous 64B chunk (4 rows x 8 bf16).
  {
    const int mtile = b0 >> 4;
    const int lrow0 = b0 & 15;               // 0,4,8,12
    u16* dstb = xf + (size_t)mtile*22*64*8;
    for (int e = tid; e < 1408; e += 256){
      int chunk = e >> 4;                    // 0..87 = kc*4 + q16
      int u     = e & 15;                    // u32 slot within 64B chunk
      int kc = chunk >> 2, q16 = chunk & 3;
      int bb = u >> 2;                       // local batch 0..3
      int j2 = (u & 3) * 2;
      int k  = kc*32 + q16*8 + j2;           // flat feature (0..703, even)
      u32 v = 0;
      if (k < 676){ int n = k/26, f = k - n*26; v = *(const u32*)&xs[(bb*32 + n)*36 + f]; }
      *(u32*)&dstb[((kc*64 + q16*16 + lrow0 + bb) << 3) + j2] = v;
    }
  }
}

// ---------------------------------------------------------------------------
// MLP: out = leaky(xf @ W1 + b1, 0.2) @ W2 + b2.  BM=32, grid 512 (2/CU,
// 8 waves/CU). Barrier-free, LDS-free K-loop with 2-stage register prefetch;
// all fragments coalesced (1KB/wave) from swizzled layouts. Fused W2 head.
// ---------------------------------------------------------------------------
__global__ __launch_bounds__(256, 2) void mlp_kernel(
    const u16* __restrict__ xf, const u16* __restrict__ w1t,
    const float* __restrict__ b1, const float* __restrict__ w2,
    const float* __restrict__ b2, float* __restrict__ out)
{
  __shared__ float b1s[256];
  __shared__ float w2s[256*3];
  __shared__ float part[4*32*3];

  const int tid  = threadIdx.x;
  const int w    = tid >> 6;
  const int lane = tid & 63;
  const int q    = lane >> 4;
  const int lm   = lane & 15;
  const int m0   = blockIdx.x * 32;
  const int mt0  = blockIdx.x * 2;         // 2 mtiles per block

  b1s[tid] = b1[tid];
  for (int e = tid; e < 768; e += 256) w2s[e] = w2[e];

  f32x4 acc[2][4];
  #pragma unroll
  for (int a = 0; a < 2; ++a)
    #pragma unroll
    for (int b = 0; b < 4; ++b) acc[a][b] = (f32x4){0.f,0.f,0.f,0.f};

  const u16* abase = xf  + ((size_t)mt0*22*64 + lane) * 8;
  const u16* bbase = w1t + (((size_t)w*4)*22*64 + lane) * 8;

  s16x8 af[2], bf[4], afn[2], bfn[4];
  #pragma unroll
  for (int mt = 0; mt < 2; ++mt) af[mt] = *(const s16x8*)(abase + (size_t)(mt*22)*64*8);
  #pragma unroll
  for (int nt = 0; nt < 4; ++nt) bf[nt] = *(const s16x8*)(bbase + (size_t)(nt*22)*64*8);

  #pragma unroll
  for (int kc = 0; kc < 22; ++kc){
    if (kc < 21){
      #pragma unroll
      for (int mt = 0; mt < 2; ++mt)
        afn[mt] = *(const s16x8*)(abase + (size_t)(mt*22 + kc + 1)*64*8);
      #pragma unroll
      for (int nt = 0; nt < 4; ++nt)
        bfn[nt] = *(const s16x8*)(bbase + (size_t)(nt*22 + kc + 1)*64*8);
    }
    #pragma unroll
    for (int mt = 0; mt < 2; ++mt)
      #pragma unroll
      for (int nt = 0; nt < 4; ++nt)
        acc[mt][nt] = MFMA16(af[mt], bf[nt], acc[mt][nt]);
    #pragma unroll
    for (int mt = 0; mt < 2; ++mt) af[mt] = afn[mt];
    #pragma unroll
    for (int nt = 0; nt < 4; ++nt) bf[nt] = bfn[nt];
  }

  // epilogue: +b1, leaky, @W2 partials, reduce over 16 lanes (cols)
  float b1l[4], w2l[4][3];
  #pragma unroll
  for (int nt = 0; nt < 4; ++nt){
    int col = w*64 + nt*16 + lm;
    b1l[nt] = b1s[col];
    w2l[nt][0] = w2s[col*3]; w2l[nt][1] = w2s[col*3+1]; w2l[nt][2] = w2s[col*3+2];
  }
  float po[2][4][3];
  #pragma unroll
  for (int mt = 0; mt < 2; ++mt)
    #pragma unroll
    for (int r = 0; r < 4; ++r){
      float s0 = 0.f, s1 = 0.f, s2 = 0.f;
      #pragma unroll
      for (int nt = 0; nt < 4; ++nt){
        float hv = acc[mt][nt][r] + b1l[nt];
        hv = (hv >= 0.f) ? hv : 0.2f*hv;
        s0 += hv*w2l[nt][0]; s1 += hv*w2l[nt][1]; s2 += hv*w2l[nt][2];
      }
      po[mt][r][0] = s0; po[mt][r][1] = s1; po[mt][r][2] = s2;
    }
  #pragma unroll
  for (int m = 1; m < 16; m <<= 1)
    #pragma unroll
    for (int mt = 0; mt < 2; ++mt)
      #pragma unroll
      for (int r = 0; r < 4; ++r)
        #pragma unroll
        for (int kk = 0; kk < 3; ++kk)
          po[mt][r][kk] += __shfl_xor(po[mt][r][kk], m);
  if (lm == 0){
    #pragma unroll
    for (int mt = 0; mt < 2; ++mt)
      #pragma unroll
      for (int r = 0; r < 4; ++r)
        #pragma unroll
        for (int kk = 0; kk < 3; ++kk)
          part[w*96 + (mt*16 + q*4 + r)*3 + kk] = po[mt][r][kk];
  }
  __syncthreads();
  if (tid < 96){
    int row = tid/3, kk = tid - row*3;
    float o = part[row*3 + kk] + part[96 + row*3 + kk]
            + part[192 + row*3 + kk] + part[288 + row*3 + kk] + b2[kk];
    out[(m0 + row)*3 + kk] = o;
  }
}

extern "C" void kernel_launch(void* const* d_in, const int* in_sizes, int n_in,
                              void* d_out, int out_size, void* d_ws, size_t ws_size,
                              hipStream_t stream)
{
  (void)in_sizes; (void)n_in; (void)out_size; (void)ws_size;
  const float* x     = (const float*)d_in[1];
  const float* W     = (const float*)d_in[2];
  const float* a_src = (const float*)d_in[3];
  const float* a_dst = (const float*)d_in[4];
  const float* W1    = (const float*)d_in[5];
  const float* b1    = (const float*)d_in[6];
  const float* W2    = (const float*)d_in[7];
  const float* b2    = (const float*)d_in[8];
  float* out = (float*)d_out;

  u16* xfinal = (u16*)d_ws;                    // [1024][22][64][8] bf16 (swz)
  u16* w1t    = xfinal + (size_t)16384*704;    // [16][22][64][8]   bf16 (swz)
  u16* wp     = w1t    + 256*704;              // [12][32][40]      bf16

  hipLaunchKernelGGL(prep_kernel, dim3(364),  dim3(256), 0, stream,
                     W, a_src, a_dst, W1, w1t, wp);
  hipLaunchKernelGGL(gat_kernel,  dim3(4096), dim3(256), 0, stream, x, wp, xfinal);
  hipLaunchKernelGGL(mlp_kernel,  dim3(512),  dim3(256), 0, stream,
                     xfinal, w1t, b1, W2, b2, out);
}

// Round 11
// 209.451 us; speedup vs baseline: 1.0634x; 1.0093x over previous
//
#include <hip/hip_runtime.h>

typedef __attribute__((ext_vector_type(8))) short s16x8;
typedef __attribute__((ext_vector_type(4))) float f32x4;
typedef unsigned short u16;
typedef unsigned int   u32;

#define MFMA16(a,b,c) __builtin_amdgcn_mfma_f32_16x16x32_bf16((a),(b),(c),0,0,0)

__device__ __forceinline__ float bf2f(u16 u){
  u32 x = ((u32)u) << 16; float f; __builtin_memcpy(&f, &x, 4); return f;
}
__device__ __forceinline__ float bflo(u32 v){   // low bf16 of packed pair
  u32 x = v << 16; float f; __builtin_memcpy(&f, &x, 4); return f;
}
__device__ __forceinline__ float bfhi(u32 v){   // high bf16 of packed pair
  u32 x = v & 0xFFFF0000u; float f; __builtin_memcpy(&f, &x, 4); return f;
}
__device__ __forceinline__ u16 f2bf(float f){
  u32 x; __builtin_memcpy(&x, &f, 4);
  x += 0x7FFFu + ((x >> 16) & 1u);   // round-to-nearest-even
  return (u16)(x >> 16);
}
#if defined(__has_builtin) && __has_builtin(__builtin_amdgcn_cvt_pk_bf16_f32)
__device__ __forceinline__ u32 pack2(float a, float b){
  return __builtin_bit_cast(u32, __builtin_amdgcn_cvt_pk_bf16_f32(a, b));
}
#else
__device__ __forceinline__ u32 pack2(float a, float b){
  return (u32)f2bf(a) | ((u32)f2bf(b) << 16);
}
#endif
#if defined(__has_builtin) && __has_builtin(__builtin_amdgcn_exp2f)
__device__ __forceinline__ float fexp2(float x){ return __builtin_amdgcn_exp2f(x); }
#else
extern "C" __device__ float __ocml_native_exp2_f32(float);
__device__ __forceinline__ float fexp2(float x){ return __ocml_native_exp2_f32(x); }
#endif

// Layouts:
// xf_swz : [mtile=1024][kc=22][lane=64][8]  A[m=lane&15][k=kc*32+(lane>>4)*8+j]
// w1_swz : [ntile=16]  [kc=22][lane=64][8]  B[k=...][n=ntile*16+(lane&15)]
// wp[l*4+h] : [32 rows o][stride 40 f];
//   rows 0..25 : 0.25 * W^T          (0.25 head-mean folded in — exact, pow2)
//   row  26    : log2e * (W @ a_src)  row 27 : log2e * (W @ a_dst)
//   rows 28..31 / cols >= 26 : 0
// gat LDS (pad-32 nodes, WAVE-PRIVATE per local batch w):
//   xs [128 rows = w*32+n][stride 36]   (n>=26 rows zero, f>=26 cols zero)
//   hsT[4 heads][28 rows o][stride 136] cols = w*32+n; 16B-aligned rows.
//     o27 pad cols poisoned -1e30 in matmul1; every private cell rewritten
//     each layer -> zero __syncthreads() in the whole 3-layer loop.

// ---------------------------------------------------------------------------
// prep: blocks 0..351: W1 -> w1_swz; blocks 352..363: wp for lh = blk-352.
// ---------------------------------------------------------------------------
__global__ __launch_bounds__(256) void prep_kernel(
    const float* __restrict__ W, const float* __restrict__ a_src,
    const float* __restrict__ a_dst, const float* __restrict__ W1,
    u16* __restrict__ w1t, u16* __restrict__ wp)
{
  const int t = threadIdx.x;
  if (blockIdx.x < 352){
    const int k = blockIdx.x * 2;            // 0..702 even
    const int n = t;
    float v0 = 0.f, v1 = 0.f;
    if (k < 676)     v0 = W1[(size_t)k*256 + n];
    if (k + 1 < 676) v1 = W1[(size_t)(k+1)*256 + n];
    const int ntile = n >> 4, lm = n & 15;
    const int kc = k >> 5, q16 = (k >> 3) & 3, j = k & 7;
    u16* dst = w1t + ((((size_t)ntile*22 + kc)*64 + q16*16 + lm) << 3) + j;
    *(u32*)dst = pack2(v0, v1);
  } else {
    const int lh = blockIdx.x - 352;         // 0..11 = l*4+h
    const float* Wlh = W + lh*676;           // [f][o]
    u16* dst = wp + lh*32*40;
    for (int e = t; e < 1280; e += 256) dst[e] = 0;
    __syncthreads();
    for (int e = t; e < 676; e += 256){      // value rows: 0.25*W^T
      int f = e/26, o = e%26;
      dst[o*40 + f] = f2bf(0.25f * Wlh[f*26 + o]);
    }
    if (t < 52){                             // score rows: log2e * (W@a)
      int sel = t/26, f = t%26;
      const float* av = (sel ? a_dst : a_src) + lh*26;
      float acc = 0.f;
      #pragma unroll
      for (int o = 0; o < 26; ++o) acc += Wlh[f*26 + o]*av[o];
      dst[(26 + sel)*40 + f] = f2bf(1.4426950408889634f * acc);
    }
  }
}

// ---------------------------------------------------------------------------
// GAT kernel: 3 fused layers, BARRIER-FREE layer loop (wave = batch for both
// matmuls; xs/hsT regions wave-private). One block = 4 batches, 256 threads,
// 4 blocks/CU. Single __syncthreads before the cooperative xf tail store.
// ---------------------------------------------------------------------------
__global__ __launch_bounds__(256, 4) void gat_kernel(
    const float* __restrict__ x, const u16* __restrict__ wp,
    u16* __restrict__ xf)
{
  __shared__ __align__(16) u16 xs [128*36];
  __shared__ __align__(16) u16 hsT[4*28*136];

  const int tid  = threadIdx.x;
  const int w    = tid >> 6;                 // wave = local batch
  const int lane = tid & 63;
  const int q    = lane >> 4;
  const int lm   = lane & 15;
  const int lmc  = (lm < 11) ? lm : 11;      // clamp for am1 row reads
  const int b0   = blockIdx.x * 4;
  const int b32  = w*32;
  const float L2E = 1.4426950408889634f;

  // poison masks for d11 (o = 16+lm = 27, node col 16+q*4+r >= 26)
  const bool pm01 = (lm == 11) && (q == 3);  // regs 0,1
  const bool pm23 = (lm == 11) && (q >= 2);  // regs 2,3

  // wave-private xs zero (own 32 rows = 576 u32), then stage own batch
  for (int e = lane; e < 576; e += 64) ((u32*)xs)[w*576 + e] = 0;
  for (int pp = lane; pp < 338; pp += 64){
    int n = pp/13, p = pp%13;
    float2 v = *(const float2*)&x[(size_t)(b0 + w)*676 + n*26 + 2*p];
    *(u32*)&xs[(b32 + n)*36 + 2*p] = pack2(v.x, v.y);
  }

  for (int l = 0; l < 3; ++l){
    // ---- matmul1: h_aug = x @ W_aug, all 4 heads for own batch ----
    {
      s16x8 af0 = *(const s16x8*)&xs[(b32      + lm)*36 + q*8];
      s16x8 af1 = *(const s16x8*)&xs[(b32 + 16 + lm)*36 + q*8];
      #pragma unroll
      for (int h = 0; h < 4; ++h){
        s16x8 bfr0 = *(const s16x8*)&wp[((l*4 + h)*32      + lm)*40 + q*8];
        s16x8 bfr1 = *(const s16x8*)&wp[((l*4 + h)*32 + 16 + lm)*40 + q*8];
        f32x4 z = {0.f,0.f,0.f,0.f};
        f32x4 d00 = MFMA16(af0, bfr0, z);   // nodes 0..15,  o = lm
        f32x4 d10 = MFMA16(af1, bfr0, z);   // nodes 16..31, o = lm
        f32x4 d01 = MFMA16(af0, bfr1, z);   // nodes 0..15,  o = 16+lm
        f32x4 d11 = MFMA16(af1, bfr1, z);   // nodes 16..31, o = 16+lm
        // poison s_dst (o=27) pad node cols >= 26
        d11[0] = pm01 ? -1e30f : d11[0];
        d11[1] = pm01 ? -1e30f : d11[1];
        d11[2] = pm23 ? -1e30f : d11[2];
        d11[3] = pm23 ? -1e30f : d11[3];
        const int rlo = (h*28 + lm)*136 + b32 + q*4;
        { uint2 uu; uu.x = pack2(d00[0], d00[1]); uu.y = pack2(d00[2], d00[3]);
          *(uint2*)&hsT[rlo] = uu; }
        { uint2 uu; uu.x = pack2(d10[0], d10[1]); uu.y = pack2(d10[2], d10[3]);
          *(uint2*)&hsT[rlo + 16] = uu; }
        if (lm < 12){
          const int rhi = (h*28 + 16 + lm)*136 + b32 + q*4;
          { uint2 uu; uu.x = pack2(d01[0], d01[1]); uu.y = pack2(d01[2], d01[3]);
            *(uint2*)&hsT[rhi] = uu; }
          { uint2 uu; uu.x = pack2(d11[0], d11[1]); uu.y = pack2(d11[2], d11[3]);
            *(uint2*)&hsT[rhi + 16] = uu; }
        }
      }
    }
    // no barrier: hsT columns b32.. are wave-private

    // ---- matmul2: out^T = h^T @ alpha^T, softmax in-register ----
    {
      f32x4 acc00 = {0,0,0,0}, acc01 = acc00, acc10 = acc00, acc11 = acc00;
      const int j0 = q*8;
      #pragma unroll
      for (int h = 0; h < 4; ++h){
        s16x8 am0 = *(const s16x8*)&hsT[(h*28      + lm )*136 + b32 + j0];
        s16x8 am1 = *(const s16x8*)&hsT[(h*28 + 16 + lmc)*136 + b32 + j0];
        uint4 sdv = *(const uint4*)&hsT[(h*28 + 27      )*136 + b32 + j0];
        float sd2[8];
        sd2[0] = bflo(sdv.x); sd2[1] = bfhi(sdv.x);
        sd2[2] = bflo(sdv.y); sd2[3] = bfhi(sdv.y);
        sd2[4] = bflo(sdv.z); sd2[5] = bfhi(sdv.z);
        sd2[6] = bflo(sdv.w); sd2[7] = bfhi(sdv.w);
        #pragma unroll
        for (int nt = 0; nt < 2; ++nt){
          int i = nt*16 + lm;
          float si2 = bf2f(hsT[(h*28 + 26)*136 + b32 + i]);  // pre-scaled
          float p[8]; float loc = 0.f;
          #pragma unroll
          for (int jj = 0; jj < 8; ++jj){
            float e = si2 + sd2[jj];
            e = fmaxf(e, 0.2f*e);                  // leaky_relu (log2 domain)
            float pv = fexp2(e);                   // pad cols: exp2(-1e30)=0
            p[jj] = pv; loc += pv;
          }
          float tot = loc;
          tot += __shfl_xor(tot, 16);
          tot += __shfl_xor(tot, 32);
          float rinv = __builtin_amdgcn_rcpf(tot);
          uint4 bu = { pack2(p[0]*rinv, p[1]*rinv), pack2(p[2]*rinv, p[3]*rinv),
                       pack2(p[4]*rinv, p[5]*rinv), pack2(p[6]*rinv, p[7]*rinv) };
          s16x8 bfrag = __builtin_bit_cast(s16x8, bu);
          if (nt == 0){ acc00 = MFMA16(am0, bfrag, acc00);
                        acc10 = MFMA16(am1, bfrag, acc10); }
          else        { acc01 = MFMA16(am0, bfrag, acc01);
                        acc11 = MFMA16(am1, bfrag, acc11); }
        }
      }
      // epilogue: heads pre-meaned (0.25 in wp), ELU, write next-layer xs
      #pragma unroll
      for (int nt = 0; nt < 2; ++nt){
        int i = nt*16 + lm;
        if (i < 26){
          int rowb = (b32 + i)*36;
          #pragma unroll
          for (int mt = 0; mt < 2; ++mt){
            f32x4 a = (mt == 0) ? (nt == 0 ? acc00 : acc01)
                                : (nt == 0 ? acc10 : acc11);
            int f0 = mt*16 + q*4;
            float v0 = a[0], v1 = a[1], v2 = a[2], v3 = a[3];
            v0 = (v0 > 0.f) ? v0 : (fexp2(v0*L2E) - 1.f);
            v1 = (v1 > 0.f) ? v1 : (fexp2(v1*L2E) - 1.f);
            v2 = (v2 > 0.f) ? v2 : (fexp2(v2*L2E) - 1.f);
            v3 = (v3 > 0.f) ? v3 : (fexp2(v3*L2E) - 1.f);
            if (f0 <= 20){
              uint2 uu; uu.x = pack2(v0, v1); uu.y = pack2(v2, v3);
              *(uint2*)&xs[rowb + f0] = uu;
            } else if (f0 == 24){
              *(u32*)&xs[rowb + 24] = pack2(v0, v1);
            }
          }
        }
      }
    }
    // no barrier: xs rows b32.. are wave-private
  }
  __syncthreads();   // tail store mixes batches within 64B chunks
  // store x_final into swizzled A-fragment layout, destination-linear:
  // each 16-thread group writes one contiguous 64B chunk (4 rows x 8 bf16).
  {
    const int mtile = b0 >> 4;
    const int lrow0 = b0 & 15;               // 0,4,8,12
    u16* dstb = xf + (size_t)mtile*22*64*8;
    for (int e = tid; e < 1408; e += 256){
      int chunk = e >> 4;                    // 0..87 = kc*4 + q16
      int u     = e & 15;                    // u32 slot within 64B chunk
      int kc = chunk >> 2, q16 = chunk & 3;
      int bb = u >> 2;                       // local batch 0..3
      int j2 = (u & 3) * 2;
      int k  = kc*32 + q16*8 + j2;           // flat feature (0..703, even)
      u32 v = 0;
      if (k < 676){ int n = k/26, f = k - n*26; v = *(const u32*)&xs[(bb*32 + n)*36 + f]; }
      *(u32*)&dstb[((kc*64 + q16*16 + lrow0 + bb) << 3) + j2] = v;
    }
  }
}

// ---------------------------------------------------------------------------
// MLP: out = leaky(xf @ W1 + b1, 0.2) @ W2 + b2.  BM=32, grid 512 (2/CU,
// 8 waves/CU). Barrier-free, LDS-free K-loop with 2-stage register prefetch;
// all fragments coalesced (1KB/wave) from swizzled layouts. Fused W2 head.
// ---------------------------------------------------------------------------
__global__ __launch_bounds__(256, 2) void mlp_kernel(
    const u16* __restrict__ xf, const u16* __restrict__ w1t,
    const float* __restrict__ b1, const float* __restrict__ w2,
    const float* __restrict__ b2, float* __restrict__ out)
{
  __shared__ float b1s[256];
  __shared__ float w2s[256*3];
  __shared__ float part[4*32*3];

  const int tid  = threadIdx.x;
  const int w    = tid >> 6;
  const int lane = tid & 63;
  const int q    = lane >> 4;
  const int lm   = lane & 15;
  const int m0   = blockIdx.x * 32;
  const int mt0  = blockIdx.x * 2;         // 2 mtiles per block

  b1s[tid] = b1[tid];
  for (int e = tid; e < 768; e += 256) w2s[e] = w2[e];

  f32x4 acc[2][4];
  #pragma unroll
  for (int a = 0; a < 2; ++a)
    #pragma unroll
    for (int b = 0; b < 4; ++b) acc[a][b] = (f32x4){0.f,0.f,0.f,0.f};

  const u16* abase = xf  + ((size_t)mt0*22*64 + lane) * 8;
  const u16* bbase = w1t + (((size_t)w*4)*22*64 + lane) * 8;

  s16x8 af[2], bf[4], afn[2], bfn[4];
  #pragma unroll
  for (int mt = 0; mt < 2; ++mt) af[mt] = *(const s16x8*)(abase + (size_t)(mt*22)*64*8);
  #pragma unroll
  for (int nt = 0; nt < 4; ++nt) bf[nt] = *(const s16x8*)(bbase + (size_t)(nt*22)*64*8);

  #pragma unroll
  for (int kc = 0; kc < 22; ++kc){
    if (kc < 21){
      #pragma unroll
      for (int mt = 0; mt < 2; ++mt)
        afn[mt] = *(const s16x8*)(abase + (size_t)(mt*22 + kc + 1)*64*8);
      #pragma unroll
      for (int nt = 0; nt < 4; ++nt)
        bfn[nt] = *(const s16x8*)(bbase + (size_t)(nt*22 + kc + 1)*64*8);
    }
    #pragma unroll
    for (int mt = 0; mt < 2; ++mt)
      #pragma unroll
      for (int nt = 0; nt < 4; ++nt)
        acc[mt][nt] = MFMA16(af[mt], bf[nt], acc[mt][nt]);
    #pragma unroll
    for (int mt = 0; mt < 2; ++mt) af[mt] = afn[mt];
    #pragma unroll
    for (int nt = 0; nt < 4; ++nt) bf[nt] = bfn[nt];
  }

  // epilogue: +b1, leaky, @W2 partials, reduce over 16 lanes (cols)
  float b1l[4], w2l[4][3];
  #pragma unroll
  for (int nt = 0; nt < 4; ++nt){
    int col = w*64 + nt*16 + lm;
    b1l[nt] = b1s[col];
    w2l[nt][0] = w2s[col*3]; w2l[nt][1] = w2s[col*3+1]; w2l[nt][2] = w2s[col*3+2];
  }
  float po[2][4][3];
  #pragma unroll
  for (int mt = 0; mt < 2; ++mt)
    #pragma unroll
    for (int r = 0; r < 4; ++r){
      float s0 = 0.f, s1 = 0.f, s2 = 0.f;
      #pragma unroll
      for (int nt = 0; nt < 4; ++nt){
        float hv = acc[mt][nt][r] + b1l[nt];
        hv = (hv >= 0.f) ? hv : 0.2f*hv;
        s0 += hv*w2l[nt][0]; s1 += hv*w2l[nt][1]; s2 += hv*w2l[nt][2];
      }
      po[mt][r][0] = s0; po[mt][r][1] = s1; po[mt][r][2] = s2;
    }
  #pragma unroll
  for (int m = 1; m < 16; m <<= 1)
    #pragma unroll
    for (int mt = 0; mt < 2; ++mt)
      #pragma unroll
      for (int r = 0; r < 4; ++r)
        #pragma unroll
        for (int kk = 0; kk < 3; ++kk)
          po[mt][r][kk] += __shfl_xor(po[mt][r][kk], m);
  if (lm == 0){
    #pragma unroll
    for (int mt = 0; mt < 2; ++mt)
      #pragma unroll
      for (int r = 0; r < 4; ++r)
        #pragma unroll
        for (int kk = 0; kk < 3; ++kk)
          part[w*96 + (mt*16 + q*4 + r)*3 + kk] = po[mt][r][kk];
  }
  __syncthreads();
  if (tid < 96){
    int row = tid/3, kk = tid - row*3;
    float o = part[row*3 + kk] + part[96 + row*3 + kk]
            + part[192 + row*3 + kk] + part[288 + row*3 + kk] + b2[kk];
    out[(m0 + row)*3 + kk] = o;
  }
}

extern "C" void kernel_launch(void* const* d_in, const int* in_sizes, int n_in,
                              void* d_out, int out_size, void* d_ws, size_t ws_size,
                              hipStream_t stream)
{
  (void)in_sizes; (void)n_in; (void)out_size; (void)ws_size;
  const float* x     = (const float*)d_in[1];
  const float* W     = (const float*)d_in[2];
  const float* a_src = (const float*)d_in[3];
  const float* a_dst = (const float*)d_in[4];
  const float* W1    = (const float*)d_in[5];
  const float* b1    = (const float*)d_in[6];
  const float* W2    = (const float*)d_in[7];
  const float* b2    = (const float*)d_in[8];
  float* out = (float*)d_out;

  u16* xfinal = (u16*)d_ws;                    // [1024][22][64][8] bf16 (swz)
  u16* w1t    = xfinal + (size_t)16384*704;    // [16][22][64][8]   bf16 (swz)
  u16* wp     = w1t    + 256*704;              // [12][32][40]      bf16

  hipLaunchKernelGGL(prep_kernel, dim3(364),  dim3(256), 0, stream,
                     W, a_src, a_dst, W1, w1t, wp);
  hipLaunchKernelGGL(gat_kernel,  dim3(4096), dim3(256), 0, stream, x, wp, xfinal);
  hipLaunchKernelGGL(mlp_kernel,  dim3(512),  dim3(256), 0, stream,
                     xfinal, w1t, b1, W2, b2, out);
}

// Round 12
// 207.855 us; speedup vs baseline: 1.0716x; 1.0077x over previous
//
#include <hip/hip_runtime.h>

typedef __attribute__((ext_vector_type(8))) short s16x8;
typedef __attribute__((ext_vector_type(4))) float f32x4;
typedef unsigned short u16;
typedef unsigned int   u32;

#define MFMA16(a,b,c) __builtin_amdgcn_mfma_f32_16x16x32_bf16((a),(b),(c),0,0,0)

__device__ __forceinline__ float bf2f(u16 u){
  u32 x = ((u32)u) << 16; float f; __builtin_memcpy(&f, &x, 4); return f;
}
__device__ __forceinline__ float bflo(u32 v){   // low bf16 of packed pair
  u32 x = v << 16; float f; __builtin_memcpy(&f, &x, 4); return f;
}
__device__ __forceinline__ float bfhi(u32 v){   // high bf16 of packed pair
  u32 x = v & 0xFFFF0000u; float f; __builtin_memcpy(&f, &x, 4); return f;
}
__device__ __forceinline__ u16 f2bf(float f){
  u32 x; __builtin_memcpy(&x, &f, 4);
  x += 0x7FFFu + ((x >> 16) & 1u);   // round-to-nearest-even
  return (u16)(x >> 16);
}
#if defined(__has_builtin) && __has_builtin(__builtin_amdgcn_cvt_pk_bf16_f32)
__device__ __forceinline__ u32 pack2(float a, float b){
  return __builtin_bit_cast(u32, __builtin_amdgcn_cvt_pk_bf16_f32(a, b));
}
#else
__device__ __forceinline__ u32 pack2(float a, float b){
  return (u32)f2bf(a) | ((u32)f2bf(b) << 16);
}
#endif
#if defined(__has_builtin) && __has_builtin(__builtin_amdgcn_exp2f)
__device__ __forceinline__ float fexp2(float x){ return __builtin_amdgcn_exp2f(x); }
#else
extern "C" __device__ float __ocml_native_exp2_f32(float);
__device__ __forceinline__ float fexp2(float x){ return __ocml_native_exp2_f32(x); }
#endif

// Layouts:
// xf_swz : [mtile=1024][kc=22][lane=64][8]  A[m=lane&15][k=kc*32+(lane>>4)*8+j]
// w1_swz : [ntile=16]  [kc=22][lane=64][8]  B[k=...][n=ntile*16+(lane&15)]
// wp[l*4+h] : [32 rows o][stride 40 f];
//   rows 0..25 : 0.25 * W^T          (0.25 head-mean folded in — exact, pow2)
//   row  26    : log2e * (W @ a_src)  row 27 : log2e * (W @ a_dst)
//   rows 28..31 / cols >= 26 : 0
// gat LDS (pad-32 nodes, WAVE-PRIVATE per local batch w):
//   xs [128 rows = w*32+n][stride 32]   rows 16B-aligned (64B) -> af loads are
//     ds_read_b128; row-to-row bank shift 16 words => 2-way aliasing (free).
//   hsT[4 heads][28 rows o][stride 136] cols = w*32+n; 16B-aligned rows.
//     o27 pad cols poisoned -1e30 in matmul1; every private cell rewritten
//     each layer -> zero __syncthreads() in the whole 3-layer loop.

// ---------------------------------------------------------------------------
// prep: blocks 0..351: W1 -> w1_swz; blocks 352..363: wp for lh = blk-352.
// ---------------------------------------------------------------------------
__global__ __launch_bounds__(256) void prep_kernel(
    const float* __restrict__ W, const float* __restrict__ a_src,
    const float* __restrict__ a_dst, const float* __restrict__ W1,
    u16* __restrict__ w1t, u16* __restrict__ wp)
{
  const int t = threadIdx.x;
  if (blockIdx.x < 352){
    const int k = blockIdx.x * 2;            // 0..702 even
    const int n = t;
    float v0 = 0.f, v1 = 0.f;
    if (k < 676)     v0 = W1[(size_t)k*256 + n];
    if (k + 1 < 676) v1 = W1[(size_t)(k+1)*256 + n];
    const int ntile = n >> 4, lm = n & 15;
    const int kc = k >> 5, q16 = (k >> 3) & 3, j = k & 7;
    u16* dst = w1t + ((((size_t)ntile*22 + kc)*64 + q16*16 + lm) << 3) + j;
    *(u32*)dst = pack2(v0, v1);
  } else {
    const int lh = blockIdx.x - 352;         // 0..11 = l*4+h
    const float* Wlh = W + lh*676;           // [f][o]
    u16* dst = wp + lh*32*40;
    for (int e = t; e < 1280; e += 256) dst[e] = 0;
    __syncthreads();
    for (int e = t; e < 676; e += 256){      // value rows: 0.25*W^T
      int f = e/26, o = e%26;
      dst[o*40 + f] = f2bf(0.25f * Wlh[f*26 + o]);
    }
    if (t < 52){                             // score rows: log2e * (W@a)
      int sel = t/26, f = t%26;
      const float* av = (sel ? a_dst : a_src) + lh*26;
      float acc = 0.f;
      #pragma unroll
      for (int o = 0; o < 26; ++o) acc += Wlh[f*26 + o]*av[o];
      dst[(26 + sel)*40 + f] = f2bf(1.4426950408889634f * acc);
    }
  }
}

// ---------------------------------------------------------------------------
// GAT kernel: 3 fused layers, barrier-free layer loop (wave = batch for both
// matmuls; xs/hsT regions wave-private). One block = 4 batches, 256 threads,
// 4 blocks/CU. Single __syncthreads before the cooperative xf tail store.
// ---------------------------------------------------------------------------
__global__ __launch_bounds__(256, 4) void gat_kernel(
    const float* __restrict__ x, const u16* __restrict__ wp,
    u16* __restrict__ xf)
{
  __shared__ __align__(16) u16 xs [128*32];
  __shared__ __align__(16) u16 hsT[4*28*136];

  const int tid  = threadIdx.x;
  const int w    = tid >> 6;                 // wave = local batch
  const int lane = tid & 63;
  const int q    = lane >> 4;
  const int lm   = lane & 15;
  const int lmc  = (lm < 11) ? lm : 11;      // clamp for am1 row reads
  const int b0   = blockIdx.x * 4;
  const int b32  = w*32;
  const float L2E = 1.4426950408889634f;

  // poison masks for d11 (o = 16+lm = 27, node col 16+q*4+r >= 26)
  const bool pm01 = (lm == 11) && (q == 3);  // regs 0,1
  const bool pm23 = (lm == 11) && (q >= 2);  // regs 2,3

  // wave-private xs zero (own 32 rows = 512 u32), then stage own batch
  for (int e = lane; e < 512; e += 64) ((u32*)xs)[w*512 + e] = 0;
  for (int pp = lane; pp < 338; pp += 64){
    int n = pp/13, p = pp%13;
    float2 v = *(const float2*)&x[(size_t)(b0 + w)*676 + n*26 + 2*p];
    *(u32*)&xs[((b32 + n) << 5) + 2*p] = pack2(v.x, v.y);
  }

  for (int l = 0; l < 3; ++l){
    // ---- matmul1: h_aug = x @ W_aug, all 4 heads for own batch ----
    {
      s16x8 af0 = *(const s16x8*)&xs[((b32      + lm) << 5) + q*8];
      s16x8 af1 = *(const s16x8*)&xs[((b32 + 16 + lm) << 5) + q*8];
      #pragma unroll
      for (int h = 0; h < 4; ++h){
        s16x8 bfr0 = *(const s16x8*)&wp[((l*4 + h)*32      + lm)*40 + q*8];
        s16x8 bfr1 = *(const s16x8*)&wp[((l*4 + h)*32 + 16 + lm)*40 + q*8];
        f32x4 z = {0.f,0.f,0.f,0.f};
        f32x4 d00 = MFMA16(af0, bfr0, z);   // nodes 0..15,  o = lm
        f32x4 d10 = MFMA16(af1, bfr0, z);   // nodes 16..31, o = lm
        f32x4 d01 = MFMA16(af0, bfr1, z);   // nodes 0..15,  o = 16+lm
        f32x4 d11 = MFMA16(af1, bfr1, z);   // nodes 16..31, o = 16+lm
        // poison s_dst (o=27) pad node cols >= 26
        d11[0] = pm01 ? -1e30f : d11[0];
        d11[1] = pm01 ? -1e30f : d11[1];
        d11[2] = pm23 ? -1e30f : d11[2];
        d11[3] = pm23 ? -1e30f : d11[3];
        const int rlo = (h*28 + lm)*136 + b32 + q*4;
        { uint2 uu; uu.x = pack2(d00[0], d00[1]); uu.y = pack2(d00[2], d00[3]);
          *(uint2*)&hsT[rlo] = uu; }
        { uint2 uu; uu.x = pack2(d10[0], d10[1]); uu.y = pack2(d10[2], d10[3]);
          *(uint2*)&hsT[rlo + 16] = uu; }
        if (lm < 12){
          const int rhi = (h*28 + 16 + lm)*136 + b32 + q*4;
          { uint2 uu; uu.x = pack2(d01[0], d01[1]); uu.y = pack2(d01[2], d01[3]);
            *(uint2*)&hsT[rhi] = uu; }
          { uint2 uu; uu.x = pack2(d11[0], d11[1]); uu.y = pack2(d11[2], d11[3]);
            *(uint2*)&hsT[rhi + 16] = uu; }
        }
      }
    }
    // no barrier: hsT columns b32.. are wave-private

    // ---- matmul2: out^T = h^T @ alpha^T, softmax in-register ----
    {
      f32x4 acc00 = {0,0,0,0}, acc01 = acc00, acc10 = acc00, acc11 = acc00;
      const int j0 = q*8;
      #pragma unroll
      for (int h = 0; h < 4; ++h){
        s16x8 am0 = *(const s16x8*)&hsT[(h*28      + lm )*136 + b32 + j0];
        s16x8 am1 = *(const s16x8*)&hsT[(h*28 + 16 + lmc)*136 + b32 + j0];
        uint4 sdv = *(const uint4*)&hsT[(h*28 + 27      )*136 + b32 + j0];
        float sd2[8];
        sd2[0] = bflo(sdv.x); sd2[1] = bfhi(sdv.x);
        sd2[2] = bflo(sdv.y); sd2[3] = bfhi(sdv.y);
        sd2[4] = bflo(sdv.z); sd2[5] = bfhi(sdv.z);
        sd2[6] = bflo(sdv.w); sd2[7] = bfhi(sdv.w);
        #pragma unroll
        for (int nt = 0; nt < 2; ++nt){
          int i = nt*16 + lm;
          float si2 = bf2f(hsT[(h*28 + 26)*136 + b32 + i]);  // pre-scaled
          float p[8]; float loc = 0.f;
          #pragma unroll
          for (int jj = 0; jj < 8; ++jj){
            float e = si2 + sd2[jj];
            e = fmaxf(e, 0.2f*e);                  // leaky_relu (log2 domain)
            float pv = fexp2(e);                   // pad cols: exp2(-1e30)=0
            p[jj] = pv; loc += pv;
          }
          float tot = loc;
          tot += __shfl_xor(tot, 16);
          tot += __shfl_xor(tot, 32);
          float rinv = __builtin_amdgcn_rcpf(tot);
          uint4 bu = { pack2(p[0]*rinv, p[1]*rinv), pack2(p[2]*rinv, p[3]*rinv),
                       pack2(p[4]*rinv, p[5]*rinv), pack2(p[6]*rinv, p[7]*rinv) };
          s16x8 bfrag = __builtin_bit_cast(s16x8, bu);
          if (nt == 0){ acc00 = MFMA16(am0, bfrag, acc00);
                        acc10 = MFMA16(am1, bfrag, acc10); }
          else        { acc01 = MFMA16(am0, bfrag, acc01);
                        acc11 = MFMA16(am1, bfrag, acc11); }
        }
      }
      // epilogue: heads pre-meaned (0.25 in wp), ELU, write next-layer xs
      #pragma unroll
      for (int nt = 0; nt < 2; ++nt){
        int i = nt*16 + lm;
        if (i < 26){
          int rowb = (b32 + i) << 5;
          #pragma unroll
          for (int mt = 0; mt < 2; ++mt){
            f32x4 a = (mt == 0) ? (nt == 0 ? acc00 : acc01)
                                : (nt == 0 ? acc10 : acc11);
            int f0 = mt*16 + q*4;
            float v0 = a[0], v1 = a[1], v2 = a[2], v3 = a[3];
            v0 = (v0 > 0.f) ? v0 : (fexp2(v0*L2E) - 1.f);
            v1 = (v1 > 0.f) ? v1 : (fexp2(v1*L2E) - 1.f);
            v2 = (v2 > 0.f) ? v2 : (fexp2(v2*L2E) - 1.f);
            v3 = (v3 > 0.f) ? v3 : (fexp2(v3*L2E) - 1.f);
            if (f0 <= 20){
              uint2 uu; uu.x = pack2(v0, v1); uu.y = pack2(v2, v3);
              *(uint2*)&xs[rowb + f0] = uu;
            } else if (f0 == 24){
              *(u32*)&xs[rowb + 24] = pack2(v0, v1);
            }
          }
        }
      }
    }
    // no barrier: xs rows b32.. are wave-private
  }
  __syncthreads();   // tail store mixes batches within 64B chunks
  // store x_final into swizzled A-fragment layout, destination-linear:
  // each 16-thread group writes one contiguous 64B chunk (4 rows x 8 bf16).
  {
    const int mtile = b0 >> 4;
    const int lrow0 = b0 & 15;               // 0,4,8,12
    u16* dstb = xf + (size_t)mtile*22*64*8;
    for (int e = tid; e < 1408; e += 256){
      int chunk = e >> 4;                    // 0..87 = kc*4 + q16
      int u     = e & 15;                    // u32 slot within 64B chunk
      int kc = chunk >> 2, q16 = chunk & 3;
      int bb = u >> 2;                       // local batch 0..3
      int j2 = (u & 3) * 2;
      int k  = kc*32 + q16*8 + j2;           // flat feature (0..703, even)
      u32 v = 0;
      if (k < 676){ int n = k/26, f = k - n*26; v = *(const u32*)&xs[((bb*32 + n) << 5) + f]; }
      *(u32*)&dstb[((kc*64 + q16*16 + lrow0 + bb) << 3) + j2] = v;
    }
  }
}

// ---------------------------------------------------------------------------
// MLP: out = leaky(xf @ W1 + b1, 0.2) @ W2 + b2.  BM=32, grid 512 (2/CU,
// 8 waves/CU). Barrier-free, LDS-free K-loop with 2-stage register prefetch;
// all fragments coalesced (1KB/wave) from swizzled layouts. Fused W2 head.
// ---------------------------------------------------------------------------
__global__ __launch_bounds__(256, 2) void mlp_kernel(
    const u16* __restrict__ xf, const u16* __restrict__ w1t,
    const float* __restrict__ b1, const float* __restrict__ w2,
    const float* __restrict__ b2, float* __restrict__ out)
{
  __shared__ float b1s[256];
  __shared__ float w2s[256*3];
  __shared__ float part[4*32*3];

  const int tid  = threadIdx.x;
  const int w    = tid >> 6;
  const int lane = tid & 63;
  const int q    = lane >> 4;
  const int lm   = lane & 15;
  const int m0   = blockIdx.x * 32;
  const int mt0  = blockIdx.x * 2;         // 2 mtiles per block

  b1s[tid] = b1[tid];
  for (int e = tid; e < 768; e += 256) w2s[e] = w2[e];

  f32x4 acc[2][4];
  #pragma unroll
  for (int a = 0; a < 2; ++a)
    #pragma unroll
    for (int b = 0; b < 4; ++b) acc[a][b] = (f32x4){0.f,0.f,0.f,0.f};

  const u16* abase = xf  + ((size_t)mt0*22*64 + lane) * 8;
  const u16* bbase = w1t + (((size_t)w*4)*22*64 + lane) * 8;

  s16x8 af[2], bf[4], afn[2], bfn[4];
  #pragma unroll
  for (int mt = 0; mt < 2; ++mt) af[mt] = *(const s16x8*)(abase + (size_t)(mt*22)*64*8);
  #pragma unroll
  for (int nt = 0; nt < 4; ++nt) bf[nt] = *(const s16x8*)(bbase + (size_t)(nt*22)*64*8);

  #pragma unroll
  for (int kc = 0; kc < 22; ++kc){
    if (kc < 21){
      #pragma unroll
      for (int mt = 0; mt < 2; ++mt)
        afn[mt] = *(const s16x8*)(abase + (size_t)(mt*22 + kc + 1)*64*8);
      #pragma unroll
      for (int nt = 0; nt < 4; ++nt)
        bfn[nt] = *(const s16x8*)(bbase + (size_t)(nt*22 + kc + 1)*64*8);
    }
    #pragma unroll
    for (int mt = 0; mt < 2; ++mt)
      #pragma unroll
      for (int nt = 0; nt < 4; ++nt)
        acc[mt][nt] = MFMA16(af[mt], bf[nt], acc[mt][nt]);
    #pragma unroll
    for (int mt = 0; mt < 2; ++mt) af[mt] = afn[mt];
    #pragma unroll
    for (int nt = 0; nt < 4; ++nt) bf[nt] = bfn[nt];
  }

  // epilogue: +b1, leaky, @W2 partials, reduce over 16 lanes (cols)
  float b1l[4], w2l[4][3];
  #pragma unroll
  for (int nt = 0; nt < 4; ++nt){
    int col = w*64 + nt*16 + lm;
    b1l[nt] = b1s[col];
    w2l[nt][0] = w2s[col*3]; w2l[nt][1] = w2s[col*3+1]; w2l[nt][2] = w2s[col*3+2];
  }
  float po[2][4][3];
  #pragma unroll
  for (int mt = 0; mt < 2; ++mt)
    #pragma unroll
    for (int r = 0; r < 4; ++r){
      float s0 = 0.f, s1 = 0.f, s2 = 0.f;
      #pragma unroll
      for (int nt = 0; nt < 4; ++nt){
        float hv = acc[mt][nt][r] + b1l[nt];
        hv = (hv >= 0.f) ? hv : 0.2f*hv;
        s0 += hv*w2l[nt][0]; s1 += hv*w2l[nt][1]; s2 += hv*w2l[nt][2];
      }
      po[mt][r][0] = s0; po[mt][r][1] = s1; po[mt][r][2] = s2;
    }
  #pragma unroll
  for (int m = 1; m < 16; m <<= 1)
    #pragma unroll
    for (int mt = 0; mt < 2; ++mt)
      #pragma unroll
      for (int r = 0; r < 4; ++r)
        #pragma unroll
        for (int kk = 0; kk < 3; ++kk)
          po[mt][r][kk] += __shfl_xor(po[mt][r][kk], m);
  if (lm == 0){
    #pragma unroll
    for (int mt = 0; mt < 2; ++mt)
      #pragma unroll
      for (int r = 0; r < 4; ++r)
        #pragma unroll
        for (int kk = 0; kk < 3; ++kk)
          part[w*96 + (mt*16 + q*4 + r)*3 + kk] = po[mt][r][kk];
  }
  __syncthreads();
  if (tid < 96){
    int row = tid/3, kk = tid - row*3;
    float o = part[row*3 + kk] + part[96 + row*3 + kk]
            + part[192 + row*3 + kk] + part[288 + row*3 + kk] + b2[kk];
    out[(m0 + row)*3 + kk] = o;
  }
}

extern "C" void kernel_launch(void* const* d_in, const int* in_sizes, int n_in,
                              void* d_out, int out_size, void* d_ws, size_t ws_size,
                              hipStream_t stream)
{
  (void)in_sizes; (void)n_in; (void)out_size; (void)ws_size;
  const float* x     = (const float*)d_in[1];
  const float* W     = (const float*)d_in[2];
  const float* a_src = (const float*)d_in[3];
  const float* a_dst = (const float*)d_in[4];
  const float* W1    = (const float*)d_in[5];
  const float* b1    = (const float*)d_in[6];
  const float* W2    = (const float*)d_in[7];
  const float* b2    = (const float*)d_in[8];
  float* out = (float*)d_out;

  u16* xfinal = (u16*)d_ws;                    // [1024][22][64][8] bf16 (swz)
  u16* w1t    = xfinal + (size_t)16384*704;    // [16][22][64][8]   bf16 (swz)
  u16* wp     = w1t    + 256*704;              // [12][32][40]      bf16

  hipLaunchKernelGGL(prep_kernel, dim3(364),  dim3(256), 0, stream,
                     W, a_src, a_dst, W1, w1t, wp);
  hipLaunchKernelGGL(gat_kernel,  dim3(4096), dim3(256), 0, stream, x, wp, xfinal);
  hipLaunchKernelGGL(mlp_kernel,  dim3(512),  dim3(256), 0, stream,
                     xfinal, w1t, b1, W2, b2, out);
}